// Round 5
// baseline (522.215 us; speedup 1.0000x reference)
//
#include <hip/hip_runtime.h>
#include <hip/hip_bf16.h>
#include <cstdint>

#define DEV __device__ __forceinline__

using f32x4  = __attribute__((ext_vector_type(4))) float;
using bf16x8 = __attribute__((ext_vector_type(8))) __bf16;

static constexpr int D_    = 512;
static constexpr int ROWS  = 2048;   // 4 batches x 512 tokens ([A|C|B])
static constexpr int F_    = 2048;
static constexpr int NEXP  = 14;     // 4 (A) + 6 (C) + 4 (B)
static constexpr int NENT  = 3072;   // exact routed entries: 1024 + 1024 + 1024
static constexpr int FCOLS = 512;    // F-split pass width (4 passes)

DEV unsigned short f2bf(float f) {
  unsigned int u = __builtin_bit_cast(unsigned int, f);
  unsigned int r = u + 0x7FFFu + ((u >> 16) & 1u);
  return (unsigned short)(r >> 16);
}
DEV float bf2f(unsigned short h) {
  unsigned int u = ((unsigned int)h) << 16;
  return __builtin_bit_cast(float, u);
}
DEV unsigned int pack2(float a, float b) {
  return (unsigned int)f2bf(a) | ((unsigned int)f2bf(b) << 16);
}
DEV float gelu_tanh(float x) {
  float x3 = x * x * x;
  return 0.5f * x * (1.0f + tanhf(0.7978845608028654f * (x + 0.044715f * x3)));
}

// ---------------- generic 128x64 bf16-MFMA GEMM core ----------------
// A: bf16 rows (per-thread gathered pointer, >=K contiguous elems, 16B aligned)
// B: fp32 weights converted to bf16 on stage.
// BTRANS=false: B is (ncols x K) row-major (NT).  BTRANS=true: B is (K x ncols) (NN).
struct SharedT { unsigned short As[128][72]; unsigned short Bs[64][72]; };

template<bool BTRANS>
DEV void gemm_core(const unsigned short* arow, const float* B, int ldb, int bcol0, int K,
                   f32x4 (&acc)[2][4], SharedT& sh)
{
  const int tid = threadIdx.x;
  const int lane = tid & 63, w = tid >> 6;
  const int ai = tid >> 1, ah = tid & 1;   // A stage: row ai, 32-bf16 half ah (4x uint4)
  const int bj = tid >> 2, bq = tid & 3;   // B stage: row bj, 16-float quarter bq
  for (int k0 = 0; k0 < K; k0 += 64) {
    __syncthreads();
    { // stage A tile 128x64 bf16: 2 threads/row, 32 bf16 (=4 uint4) each
      const uint4* src = reinterpret_cast<const uint4*>(arow + k0 + ah * 32);
      uint4 v0 = src[0], v1 = src[1], v2 = src[2], v3 = src[3];
      uint4* dst = reinterpret_cast<uint4*>(&sh.As[ai][ah * 32]);
      dst[0] = v0; dst[1] = v1; dst[2] = v2; dst[3] = v3;
    }
    if (!BTRANS) { // B rows are K-contiguous
      const float4* src = reinterpret_cast<const float4*>(B + (size_t)(bcol0 + bj) * ldb + k0 + bq * 16);
      unsigned int pk[8];
      #pragma unroll
      for (int u = 0; u < 4; ++u) {
        float4 f = src[u];
        pk[u * 2]     = pack2(f.x, f.y);
        pk[u * 2 + 1] = pack2(f.z, f.w);
      }
      uint4* dst = reinterpret_cast<uint4*>(&sh.Bs[bj][bq * 16]);
      dst[0] = make_uint4(pk[0], pk[1], pk[2], pk[3]);
      dst[1] = make_uint4(pk[4], pk[5], pk[6], pk[7]);
    } else {       // B is (K x n): transpose into Bs[n][k]
      const float4* src = reinterpret_cast<const float4*>(B + (size_t)(k0 + bj) * ldb + bcol0 + bq * 16);
      float4 f0 = src[0], f1 = src[1], f2 = src[2], f3 = src[3];
      float vals[16] = { f0.x,f0.y,f0.z,f0.w, f1.x,f1.y,f1.z,f1.w,
                         f2.x,f2.y,f2.z,f2.w, f3.x,f3.y,f3.z,f3.w };
      #pragma unroll
      for (int jj = 0; jj < 16; ++jj)
        sh.Bs[bq * 16 + jj][bj] = f2bf(vals[jj]);
    }
    __syncthreads();
    #pragma unroll
    for (int ks = 0; ks < 2; ++ks) {
      bf16x8 a[2], b[4];
      #pragma unroll
      for (int mi = 0; mi < 2; ++mi)
        a[mi] = *reinterpret_cast<const bf16x8*>(&sh.As[w * 32 + mi * 16 + (lane & 15)][ks * 32 + (lane >> 4) * 8]);
      #pragma unroll
      for (int ni = 0; ni < 4; ++ni)
        b[ni] = *reinterpret_cast<const bf16x8*>(&sh.Bs[ni * 16 + (lane & 15)][ks * 32 + (lane >> 4) * 8]);
      #pragma unroll
      for (int mi = 0; mi < 2; ++mi)
        #pragma unroll
        for (int ni = 0; ni < 4; ++ni)
          acc[mi][ni] = __builtin_amdgcn_mfma_f32_16x16x32_bf16(a[mi], b[ni], acc[mi][ni], 0, 0, 0);
    }
  }
}

// ---------------- LN (mode 0: tokens->x, mode 1: tfull->nrm) ----------------
__global__ __launch_bounds__(256) void k_ln(
    const float* tA, const float* tC, const float* tB, const float* tfull,
    const float* g3, const float* b3, unsigned short* out, int mode)
{
  int r = blockIdx.x;
  int b = r >> 9, n = r & 511;
  int grp = n < 128 ? 0 : (n < 384 ? 1 : 2);
  const float* src;
  if (mode == 0) {
    src = grp == 0 ? tA + (size_t)(b * 128 + n) * D_
        : grp == 1 ? tC + (size_t)(b * 256 + n - 128) * D_
                   : tB + (size_t)(b * 128 + n - 384) * D_;
  } else {
    src = tfull + (size_t)r * D_;
  }
  int tid = threadIdx.x, lane = tid & 63, w = tid >> 6;
  float2 v = *reinterpret_cast<const float2*>(src + tid * 2);
  float s = v.x + v.y;
  float ss = v.x * v.x + v.y * v.y;
  #pragma unroll
  for (int off = 1; off < 64; off <<= 1) { s += __shfl_xor(s, off); ss += __shfl_xor(ss, off); }
  __shared__ float red[8];
  if (lane == 0) { red[w] = s; red[4 + w] = ss; }
  __syncthreads();
  float S  = red[0] + red[1] + red[2] + red[3];
  float SS = red[4] + red[5] + red[6] + red[7];
  float mean = S * (1.0f / 512.0f);
  float var  = SS * (1.0f / 512.0f) - mean * mean;
  float inv  = rsqrtf(var + 1e-5f);
  const float* gam = g3 + grp * D_;
  const float* bet = b3 + grp * D_;
  int d0 = tid * 2;
  out[(size_t)r * D_ + d0]     = f2bf((v.x - mean) * inv * gam[d0]     + bet[d0]);
  out[(size_t)r * D_ + d0 + 1] = f2bf((v.y - mean) * inv * gam[d0 + 1] + bet[d0 + 1]);
}

// ---------------- QKV projection (one batch of 512 rows) ----------------
__global__ __launch_bounds__(256) void k_qkv(const unsigned short* x, const float* Wqkv, const float* bqkv,
                                             unsigned short* Qp, unsigned short* Kp, unsigned short* Vp,
                                             int batch)
{
  __shared__ SharedT sh;
  int bn = blockIdx.x, bm = blockIdx.y;
  int tid = threadIdx.x, lane = tid & 63, w = tid >> 6;
  const unsigned short* arow = x + (size_t)(batch * 512 + bm * 128 + (tid >> 1)) * D_;
  f32x4 acc[2][4] = {};
  gemm_core<false>(arow, Wqkv, 512, bn * 64, 512, acc, sh);
  #pragma unroll
  for (int mi = 0; mi < 2; ++mi)
  #pragma unroll
  for (int ni = 0; ni < 4; ++ni)
  #pragma unroll
  for (int j = 0; j < 4; ++j) {
    int n = bm * 128 + w * 32 + mi * 16 + ((lane >> 4) << 2) + j;   // row within batch
    int col = bn * 64 + ni * 16 + (lane & 15);
    float val = acc[mi][ni][j] + bqkv[col];
    int part = col >> 9;
    int o = col & 511, h = o >> 6, d = o & 63;
    unsigned short* dst = part == 0 ? Qp : (part == 1 ? Kp : Vp);
    dst[(size_t)(h * 512 + n) * 64 + d] = f2bf(val);
  }
}

// ---------------- flash attention (one batch) over directed tile-aligned mask ----------------
__global__ __launch_bounds__(256) void k_attn(const unsigned short* Qp, const unsigned short* Kp,
                                              const unsigned short* Vp, unsigned short* attn, int batch)
{
  __shared__ unsigned short Qs[64][72], Ks[64][72], VT[64][72], Ps[64][72];
  int qt = blockIdx.x, h = blockIdx.y;
  int tid = threadIdx.x, lane = tid & 63, w = tid >> 6;
  const unsigned short* Qb  = Qp + (size_t)h * 512 * 64;
  const unsigned short* Kbp = Kp + (size_t)h * 512 * 64;
  const unsigned short* Vbp = Vp + (size_t)h * 512 * 64;
  int i4 = tid >> 2, q4 = tid & 3;
  {
    const uint4* src = reinterpret_cast<const uint4*>(Qb + (size_t)(qt * 64 + i4) * 64 + q4 * 16);
    uint4 v0 = src[0], v1 = src[1];
    uint4* dst = reinterpret_cast<uint4*>(&Qs[i4][q4 * 16]);
    dst[0] = v0; dst[1] = v1;
  }
  int nkt = qt < 2 ? 2 : (qt < 6 ? 6 : 8);   // A: keys A; C: keys A+C; B: all
  float mrun[4] = { -1e30f, -1e30f, -1e30f, -1e30f };
  float lrun[4] = {};
  f32x4 o[4] = {};
  for (int kt = 0; kt < nkt; ++kt) {
    __syncthreads();
    { // stage K rows + V transposed
      const uint4* src = reinterpret_cast<const uint4*>(Kbp + (size_t)(kt * 64 + i4) * 64 + q4 * 16);
      uint4 v0 = src[0], v1 = src[1];
      uint4* dst = reinterpret_cast<uint4*>(&Ks[i4][q4 * 16]);
      dst[0] = v0; dst[1] = v1;
      union { uint4 u[2]; unsigned short s[16]; } vv;
      const uint4* vsrc = reinterpret_cast<const uint4*>(Vbp + (size_t)(kt * 64 + i4) * 64 + q4 * 16);
      vv.u[0] = vsrc[0]; vv.u[1] = vsrc[1];
      #pragma unroll
      for (int jj = 0; jj < 16; ++jj) VT[q4 * 16 + jj][i4] = vv.s[jj];
    }
    __syncthreads();
    f32x4 s[4] = {};
    #pragma unroll
    for (int ks = 0; ks < 2; ++ks) {
      bf16x8 aq = *reinterpret_cast<const bf16x8*>(&Qs[w * 16 + (lane & 15)][ks * 32 + (lane >> 4) * 8]);
      #pragma unroll
      for (int cc = 0; cc < 4; ++cc) {
        bf16x8 bk = *reinterpret_cast<const bf16x8*>(&Ks[cc * 16 + (lane & 15)][ks * 32 + (lane >> 4) * 8]);
        s[cc] = __builtin_amdgcn_mfma_f32_16x16x32_bf16(aq, bk, s[cc], 0, 0, 0);
      }
    }
    #pragma unroll
    for (int rr = 0; rr < 4; ++rr) {
      float s0 = s[0][rr] * 0.125f, s1 = s[1][rr] * 0.125f;
      float s2 = s[2][rr] * 0.125f, s3 = s[3][rr] * 0.125f;
      float mx = fmaxf(fmaxf(s0, s1), fmaxf(s2, s3));
      #pragma unroll
      for (int off = 1; off < 16; off <<= 1) mx = fmaxf(mx, __shfl_xor(mx, off));
      float mn = fmaxf(mrun[rr], mx);
      float al = expf(mrun[rr] - mn);
      mrun[rr] = mn;
      float p0 = expf(s0 - mn), p1 = expf(s1 - mn), p2 = expf(s2 - mn), p3 = expf(s3 - mn);
      float ps = p0 + p1 + p2 + p3;
      #pragma unroll
      for (int off = 1; off < 16; off <<= 1) ps += __shfl_xor(ps, off);
      lrun[rr] = lrun[rr] * al + ps;
      #pragma unroll
      for (int n4 = 0; n4 < 4; ++n4) o[n4][rr] *= al;
      int prow = w * 16 + ((lane >> 4) << 2) + rr;
      Ps[prow][0 * 16 + (lane & 15)] = f2bf(p0);
      Ps[prow][1 * 16 + (lane & 15)] = f2bf(p1);
      Ps[prow][2 * 16 + (lane & 15)] = f2bf(p2);
      Ps[prow][3 * 16 + (lane & 15)] = f2bf(p3);
    }
    __syncthreads();
    #pragma unroll
    for (int ks = 0; ks < 2; ++ks) {
      bf16x8 ap = *reinterpret_cast<const bf16x8*>(&Ps[w * 16 + (lane & 15)][ks * 32 + (lane >> 4) * 8]);
      #pragma unroll
      for (int n4 = 0; n4 < 4; ++n4) {
        bf16x8 bv = *reinterpret_cast<const bf16x8*>(&VT[n4 * 16 + (lane & 15)][ks * 32 + (lane >> 4) * 8]);
        o[n4] = __builtin_amdgcn_mfma_f32_16x16x32_bf16(ap, bv, o[n4], 0, 0, 0);
      }
    }
  }
  #pragma unroll
  for (int n4 = 0; n4 < 4; ++n4)
  #pragma unroll
  for (int rr = 0; rr < 4; ++rr) {
    int qrow = qt * 64 + w * 16 + ((lane >> 4) << 2) + rr;
    int col = h * 64 + n4 * 16 + (lane & 15);
    float val = o[n4][rr] / lrun[rr];
    attn[(size_t)(batch * 512 + qrow) * 512 + col] = f2bf(val);
  }
}

// ---------------- output projection + residual (writes d_out = t) ----------------
__global__ __launch_bounds__(256) void k_wo(const unsigned short* attn, const float* Wo, const float* bo,
                                            const float* tokA, const float* tokC, const float* tokB,
                                            float* out)
{
  __shared__ SharedT sh;
  int bn = blockIdx.x, bm = blockIdx.y;
  int tid = threadIdx.x, lane = tid & 63, w = tid >> 6;
  const unsigned short* arow = attn + (size_t)(bm * 128 + (tid >> 1)) * D_;
  f32x4 acc[2][4] = {};
  gemm_core<false>(arow, Wo, 512, bn * 64, 512, acc, sh);
  #pragma unroll
  for (int mi = 0; mi < 2; ++mi)
  #pragma unroll
  for (int ni = 0; ni < 4; ++ni)
  #pragma unroll
  for (int j = 0; j < 4; ++j) {
    int row = bm * 128 + w * 32 + mi * 16 + ((lane >> 4) << 2) + j;
    int col = bn * 64 + ni * 16 + (lane & 15);
    float val = acc[mi][ni][j] + bo[col];
    int b = row >> 9, n = row & 511;
    float res;
    if (n < 128)      res = tokA[(size_t)(b * 128 + n) * D_ + col];
    else if (n < 384) res = tokC[(size_t)(b * 256 + n - 128) * D_ + col];
    else              res = tokB[(size_t)(b * 128 + n - 384) * D_ + col];
    out[(size_t)row * D_ + col] = res + val;
  }
}

// ---------------- router: fp32 LN2 + fp32 logits from t (decision path all-fp32) ----------------
__global__ __launch_bounds__(256) void k_router_count(const float* t,
    const float* ln2g, const float* ln2b,
    const float* WrA, const float* brA, const float* WrC, const float* brC,
    const float* WrB, const float* brB, int* cnt, int* tokexp, float* tokgate)
{
  int w = threadIdx.x >> 6, lane = threadIdx.x & 63;
  int r = blockIdx.x * 4 + w;
  int n = r & 511;
  int grp = n < 128 ? 0 : (n < 384 ? 1 : 2);
  int E = grp == 1 ? 6 : 4;
  int k = grp == 1 ? 1 : 2;
  const float* Wr = grp == 0 ? WrA : (grp == 1 ? WrC : WrB);
  const float* br = grp == 0 ? brA : (grp == 1 ? brC : brB);
  int egbase = grp == 0 ? 0 : (grp == 1 ? 4 : 10);
  const float* tr = t + (size_t)r * D_;
  float xv[8];
  float s = 0.0f, ss = 0.0f;
  #pragma unroll
  for (int it = 0; it < 8; ++it) {
    float v = tr[it * 64 + lane];
    xv[it] = v; s += v; ss += v * v;
  }
  #pragma unroll
  for (int off = 1; off < 64; off <<= 1) { s += __shfl_xor(s, off); ss += __shfl_xor(ss, off); }
  float mean = s * (1.0f / 512.0f);
  float var  = ss * (1.0f / 512.0f) - mean * mean;
  float inv  = rsqrtf(var + 1e-5f);
  const float* gam = ln2g + grp * D_;
  const float* bet = ln2b + grp * D_;
  float acc[6] = {0, 0, 0, 0, 0, 0};
  #pragma unroll
  for (int it = 0; it < 8; ++it) {
    int d = it * 64 + lane;
    float nv = (xv[it] - mean) * inv * gam[d] + bet[d];
    for (int e = 0; e < E; ++e) acc[e] += nv * Wr[d * E + e];
  }
  #pragma unroll
  for (int e = 0; e < 6; ++e)
    #pragma unroll
    for (int off = 1; off < 64; off <<= 1) acc[e] += __shfl_xor(acc[e], off);
  if (lane == 0) {
    float p[6];
    float mx = -1e30f;
    for (int e = 0; e < E; ++e) { p[e] = acc[e] + br[e]; mx = fmaxf(mx, p[e]); }
    float sum = 0.0f;
    for (int e = 0; e < E; ++e) { p[e] = expf(p[e] - mx); sum += p[e]; }
    for (int e = 0; e < E; ++e) p[e] /= sum;
    int i1 = 0; float v1 = p[0];
    for (int e = 1; e < E; ++e) if (p[e] > v1) { v1 = p[e]; i1 = e; }
    if (k == 1) {
      tokexp[r * 2]     = egbase + i1; tokgate[r * 2]     = 1.0f;
      tokexp[r * 2 + 1] = -1;          tokgate[r * 2 + 1] = 0.0f;
      atomicAdd(&cnt[egbase + i1], 1);
    } else {
      int i2 = -1; float v2 = -1e30f;
      for (int e = 0; e < E; ++e) if (e != i1 && p[e] > v2) { v2 = p[e]; i2 = e; }
      float tot = v1 + v2;
      tokexp[r * 2]     = egbase + i1; tokgate[r * 2]     = v1 / tot;
      tokexp[r * 2 + 1] = egbase + i2; tokgate[r * 2 + 1] = v2 / tot;
      atomicAdd(&cnt[egbase + i1], 1);
      atomicAdd(&cnt[egbase + i2], 1);
    }
  }
}

// ---------------- router phase 2: exclusive prefix over 14 counts ----------------
__global__ void k_scan(const int* cnt, int* base) {
  if (threadIdx.x == 0) {
    int acc = 0;
    for (int e = 0; e < NEXP; ++e) { base[e] = acc; acc += cnt[e]; }
  }
}

// ---------------- router phase 3: scatter tokens into compact expert lists ----------------
__global__ __launch_bounds__(256) void k_scatter(const int* tokexp, const float* tokgate,
                                                 const int* base, int* cursor, int* list, float* gate)
{
  int r = blockIdx.x * 256 + threadIdx.x;
  #pragma unroll
  for (int j = 0; j < 2; ++j) {
    int e = tokexp[r * 2 + j];
    if (e >= 0) {
      int s = atomicAdd(&cursor[e], 1);
      list[base[e] + s] = r;
      gate[base[e] + s] = tokgate[r * 2 + j];
    }
  }
}

// ---------------- MoE GEMM1 (F-split): H = gelu(gather(nrm) @ W1_e + b1_e)[:, f0:f0+512] ----------------
__global__ __launch_bounds__(256) void k_moe1(const unsigned short* nrm,
    const float* W1A, const float* b1A, const float* W1C, const float* b1C,
    const float* W1B, const float* b1B,
    const int* cnt, const int* ebase, const int* list, unsigned short* H, int f0)
{
  __shared__ SharedT sh;
  int ft = blockIdx.x, tt = blockIdx.y, e = blockIdx.z;
  int c = cnt[e];
  if (tt * 128 >= c) return;
  const float *W1, *b1;
  if (e < 4)       { W1 = W1A + (size_t)e * D_ * F_;        b1 = b1A + (size_t)e * F_; }
  else if (e < 10) { W1 = W1C + (size_t)(e - 4) * D_ * F_;  b1 = b1C + (size_t)(e - 4) * F_; }
  else             { W1 = W1B + (size_t)(e - 10) * D_ * F_; b1 = b1B + (size_t)(e - 10) * F_; }
  int base = ebase[e];
  int tid = threadIdx.x, lane = tid & 63, w = tid >> 6;
  int ig = tt * 128 + (tid >> 1);
  int tok = list[base + (ig < c ? ig : c - 1)];
  const unsigned short* arow = nrm + (size_t)tok * D_;
  f32x4 acc[2][4] = {};
  gemm_core<true>(arow, W1, F_, f0 + ft * 64, 512, acc, sh);
  #pragma unroll
  for (int mi = 0; mi < 2; ++mi)
  #pragma unroll
  for (int ni = 0; ni < 4; ++ni)
  #pragma unroll
  for (int j = 0; j < 4; ++j) {
    int rl = w * 32 + mi * 16 + ((lane >> 4) << 2) + j;
    int sg = tt * 128 + rl;
    if (sg < c) {
      int col = ft * 64 + ni * 16 + (lane & 15);   // local col within pass
      float val = acc[mi][ni][j] + b1[f0 + col];
      H[(size_t)(base + sg) * FCOLS + col] = f2bf(gelu_tanh(val));
    }
  }
}

// ---------------- MoE GEMM2 (F-split): out += gate * (H @ W2_e[f0:f0+512,:] + b2_e@pass0) ----------------
__global__ __launch_bounds__(256) void k_moe2(const unsigned short* H,
    const float* W2A, const float* b2A, const float* W2C, const float* b2C,
    const float* W2B, const float* b2B,
    const int* cnt, const int* ebase, const int* list, const float* gate, float* out, int f0)
{
  __shared__ SharedT sh;
  int dt = blockIdx.x, tt = blockIdx.y, e = blockIdx.z;
  int c = cnt[e];
  if (tt * 128 >= c) return;
  const float *W2, *b2;
  if (e < 4)       { W2 = W2A + (size_t)e * F_ * D_;        b2 = b2A + (size_t)e * D_; }
  else if (e < 10) { W2 = W2C + (size_t)(e - 4) * F_ * D_;  b2 = b2C + (size_t)(e - 4) * D_; }
  else             { W2 = W2B + (size_t)(e - 10) * F_ * D_; b2 = b2B + (size_t)(e - 10) * D_; }
  W2 += (size_t)f0 * D_;   // rows [f0, f0+512)
  int base = ebase[e];
  int tid = threadIdx.x, lane = tid & 63, w = tid >> 6;
  int ig = tt * 128 + (tid >> 1);
  const unsigned short* arow = H + (size_t)(base + (ig < c ? ig : c - 1)) * FCOLS;
  f32x4 acc[2][4] = {};
  gemm_core<true>(arow, W2, 512, dt * 64, FCOLS, acc, sh);
  #pragma unroll
  for (int mi = 0; mi < 2; ++mi)
  #pragma unroll
  for (int ni = 0; ni < 4; ++ni)
  #pragma unroll
  for (int j = 0; j < 4; ++j) {
    int rl = w * 32 + mi * 16 + ((lane >> 4) << 2) + j;
    int sg = tt * 128 + rl;
    if (sg < c) {
      int col = dt * 64 + ni * 16 + (lane & 15);
      float val = acc[mi][ni][j] + (f0 == 0 ? b2[col] : 0.0f);
      int tok = list[base + sg];
      atomicAdd(&out[(size_t)tok * D_ + col], gate[base + sg] * val);
    }
  }
}

extern "C" void kernel_launch(void* const* d_in, const int* in_sizes, int n_in,
                              void* d_out, int out_size, void* d_ws, size_t ws_size,
                              hipStream_t stream)
{
  const float* tokA = (const float*)d_in[0];
  const float* tokB = (const float*)d_in[1];
  const float* tokC = (const float*)d_in[2];
  const float* ln1g = (const float*)d_in[3];
  const float* ln1b = (const float*)d_in[4];
  const float* ln2g = (const float*)d_in[5];
  const float* ln2b = (const float*)d_in[6];
  const float* Wqkv = (const float*)d_in[7];
  const float* bqkv = (const float*)d_in[8];
  const float* Wo   = (const float*)d_in[9];
  const float* bo   = (const float*)d_in[10];
  const float* WrA  = (const float*)d_in[11];
  const float* brA  = (const float*)d_in[12];
  const float* W1A  = (const float*)d_in[13];
  const float* b1A  = (const float*)d_in[14];
  const float* W2A  = (const float*)d_in[15];
  const float* b2A  = (const float*)d_in[16];
  const float* WrC  = (const float*)d_in[17];
  const float* brC  = (const float*)d_in[18];
  const float* W1C  = (const float*)d_in[19];
  const float* b1C  = (const float*)d_in[20];
  const float* W2C  = (const float*)d_in[21];
  const float* b2C  = (const float*)d_in[22];
  const float* WrB  = (const float*)d_in[23];
  const float* brB  = (const float*)d_in[24];
  const float* W1B  = (const float*)d_in[25];
  const float* b1B  = (const float*)d_in[26];
  const float* W2B  = (const float*)d_in[27];
  const float* b2B  = (const float*)d_in[28];
  float* out = (float*)d_out;

  // ---- workspace layout, total 5.83 MB, overlap only dead-before-reuse ----
  char* ws = (char*)d_ws;
  const size_t MB = 1024 * 1024;
  unsigned short* xb   = (unsigned short*)(ws);               // LN1 out -> later nrm
  unsigned short* nrm  = xb;
  unsigned short* Qp   = (unsigned short*)(ws + 2 * MB);      // per-batch QKV scratch
  unsigned short* Kp   = (unsigned short*)(ws + 2 * MB + 512 * 1024);
  unsigned short* Vp   = (unsigned short*)(ws + 3 * MB);
  unsigned short* H    = (unsigned short*)(ws + 2 * MB);      // MoE H over dead qkv/attn
  unsigned short* attn = (unsigned short*)(ws + 3 * MB + 512 * 1024);
  char* small = ws + 5 * MB + 768 * 1024;
  int*   cnt     = (int*)(small);
  int*   cursor  = (int*)(small + 64);
  int*   ebase   = (int*)(small + 128);
  int*   tokexp  = (int*)(small + 256);
  float* tokgate = (float*)(small + 256 + ROWS * 2 * 4);
  int*   list    = (int*)(small + 256 + ROWS * 4 * 4);
  float* gate    = (float*)(small + 256 + ROWS * 4 * 4 + NENT * 4);

  hipMemsetAsync(cnt, 0, 192, stream);  // cnt + cursor + ebase
  k_ln<<<ROWS, 256, 0, stream>>>(tokA, tokC, tokB, nullptr, ln1g, ln1b, xb, 0);
  for (int b = 0; b < 4; ++b) {
    k_qkv<<<dim3(24, 4), 256, 0, stream>>>(xb, Wqkv, bqkv, Qp, Kp, Vp, b);
    k_attn<<<dim3(8, 8), 256, 0, stream>>>(Qp, Kp, Vp, attn, b);
  }
  k_wo<<<dim3(8, 16), 256, 0, stream>>>(attn, Wo, bo, tokA, tokC, tokB, out);
  k_ln<<<ROWS, 256, 0, stream>>>(nullptr, nullptr, nullptr, out, ln2g, ln2b, nrm, 1);
  k_router_count<<<512, 256, 0, stream>>>(out, ln2g, ln2b, WrA, brA, WrC, brC, WrB, brB, cnt, tokexp, tokgate);
  k_scan<<<1, 64, 0, stream>>>(cnt, ebase);
  k_scatter<<<8, 256, 0, stream>>>(tokexp, tokgate, ebase, cursor, list, gate);
  for (int p = 0; p < 4; ++p) {
    int f0 = p * FCOLS;
    k_moe1<<<dim3(8, 8, 14), 256, 0, stream>>>(nrm, W1A, b1A, W1C, b1C, W1B, b1B, cnt, ebase, list, H, f0);
    k_moe2<<<dim3(8, 8, 14), 256, 0, stream>>>(H, W2A, b2A, W2C, b2C, W2B, b2B, cnt, ebase, list, gate, out, f0);
  }
}